// Round 7
// baseline (207.749 us; speedup 1.0000x reference)
//
#include <hip/hip_runtime.h>

#define IN_DIM 128
#define HID    64
#define SCAN_B 256
#define NSTRIPE 16

typedef __attribute__((ext_vector_type(4))) _Float16 f16x4;
typedef __attribute__((ext_vector_type(8))) _Float16 f16x8;
typedef __attribute__((ext_vector_type(4))) float    f32x4;

// ---------------- weight prep: f32 -> f16, transposed ----------------
__global__ void k_prep_w(const float* __restrict__ W1, const float* __restrict__ W2,
                         _Float16* __restrict__ W1T, _Float16* __restrict__ W2T) {
    int i = blockIdx.x * blockDim.x + threadIdx.x;
    if (i < IN_DIM * HID) { int k = i >> 6, c = i & 63; W1T[c * IN_DIM + k] = (_Float16)W1[i]; }
    if (i < HID * HID)    { int k = i >> 6, c = i & 63; W2T[c * HID + k]    = (_Float16)W2[i]; }
}

// ---------------- striped histogram with rank capture ----------------
// stripe k = wave-id & 15  ->  per-cacheline contention / 16
__global__ void k_hist_rank(const int* __restrict__ dst, int* __restrict__ counts_s,
                            int* __restrict__ rank, int n, int e) {
    int i = blockIdx.x * blockDim.x + threadIdx.x;
    if (i < e) {
        int k = (i >> 6) & (NSTRIPE - 1);
        rank[i] = atomicAdd(&counts_s[k * n + dst[i]], 1);
    }
}

// per-node prefix over the 16 stripes; total -> offsets[v]
__global__ void k_stripe_scan(const int* __restrict__ counts_s, int* __restrict__ P,
                              int* __restrict__ offsets, int n) {
    int v = blockIdx.x * blockDim.x + threadIdx.x;
    if (v >= n) return;
    int acc = 0;
    int pv[NSTRIPE];
    #pragma unroll
    for (int k = 0; k < NSTRIPE; ++k) { pv[k] = acc; acc += counts_s[k * n + v]; }
    #pragma unroll
    for (int k = 0; k < NSTRIPE; ++k) P[v * NSTRIPE + k] = pv[k];
    offsets[v] = acc;
}

// ---------------- scans ----------------
__global__ __launch_bounds__(SCAN_B) void k_scan1(int* __restrict__ data,
                                                  int* __restrict__ blockSums, int n) {
    __shared__ int s[SCAN_B];
    int tid = threadIdx.x;
    int gid = blockIdx.x * SCAN_B + tid;
    int v = (gid < n) ? data[gid] : 0;
    s[tid] = v;
    __syncthreads();
    for (int off = 1; off < SCAN_B; off <<= 1) {
        int t = (tid >= off) ? s[tid - off] : 0;
        __syncthreads();
        s[tid] += t;
        __syncthreads();
    }
    if (gid < n) data[gid] = s[tid] - v;
    if (tid == SCAN_B - 1) blockSums[blockIdx.x] = s[tid];
}

__global__ __launch_bounds__(512) void k_scan2(int* __restrict__ blockSums, int nb) {
    __shared__ int s[512];
    int tid = threadIdx.x;
    int v = (tid < nb) ? blockSums[tid] : 0;
    s[tid] = v;
    __syncthreads();
    for (int off = 1; off < 512; off <<= 1) {
        int t = (tid >= off) ? s[tid - off] : 0;
        __syncthreads();
        s[tid] += t;
        __syncthreads();
    }
    if (tid < nb) blockSums[tid] = s[tid] - v;
}

// scan fixup: data[v] -> row start; fold row start into P[v][*]; terminator data[n]=e
__global__ __launch_bounds__(SCAN_B) void k_scan3_fix(int* __restrict__ data,
                                                      const int* __restrict__ blockSums,
                                                      int* __restrict__ P, int n, int e) {
    int gid = blockIdx.x * SCAN_B + threadIdx.x;
    if (gid < n) {
        int off = data[gid] + blockSums[blockIdx.x];
        data[gid] = off;
        #pragma unroll
        for (int k = 0; k < NSTRIPE; ++k) P[gid * NSTRIPE + k] += off;
        if (gid == n - 1) data[n] = e;
    }
}

// ---------------- atomic-free scatter: pos = P[dst][stripe] + rank ----------------
__global__ void k_scatter(const int* __restrict__ src, const int* __restrict__ dst,
                          const float* __restrict__ ew, const int* __restrict__ rank,
                          const int* __restrict__ P, int2* __restrict__ sedge, int e) {
    int i = blockIdx.x * blockDim.x + threadIdx.x;
    if (i >= e) return;
    int k = (i >> 6) & (NSTRIPE - 1);
    int pos = P[dst[i] * NSTRIPE + k] + rank[i];
    sedge[pos] = make_int2(src[i], __float_as_int(ew[i]));
}

// ---------------- weighted degree from sorted weights + dinv ----------------
__global__ void k_deg_dinv(const int* __restrict__ rowOff, const int2* __restrict__ sedge,
                           float* __restrict__ dinv, int n) {
    int v = blockIdx.x * blockDim.x + threadIdx.x;
    if (v >= n) return;
    int s = rowOff[v], t = rowOff[v + 1];
    float a = 1.0f;                         // self-loop weight
    for (int j = s; j < t; ++j) a += __int_as_float(sedge[j].y);
    dinv[v] = rsqrtf(a);
}

// ---------------- GEMM1 (MFMA f16): g1 = (x @ W1) * dinv[row], out f16 ----------------

__global__ __launch_bounds__(256) void k_gemm1(const float* __restrict__ x,
                                               const _Float16* __restrict__ W1T,
                                               const float* __restrict__ dinv,
                                               _Float16* __restrict__ h0, int n) {
    __shared__ _Float16 sX[4][16 * IN_DIM];   // 16 KB total
    int tid  = threadIdx.x;
    int wave = tid >> 6, lane = tid & 63;
    int row0 = blockIdx.x * 64 + wave * 16;
    int col  = lane & 15, kg = lane >> 4;

    f16x8 bfrag[4][4];
    #pragma unroll
    for (int ks = 0; ks < 4; ++ks)
        #pragma unroll
        for (int ct = 0; ct < 4; ++ct)
            bfrag[ks][ct] = *(const f16x8*)(W1T + (ct * 16 + col) * IN_DIM + ks * 32 + kg * 8);

    _Float16* myX = sX[wave];
    #pragma unroll
    for (int it = 0; it < 8; ++it) {
        int idx = it * 64 + lane;
        int r = idx >> 5, c4 = idx & 31;
        int grow = row0 + r;
        float4 v = make_float4(0.f, 0.f, 0.f, 0.f);
        if (grow < n) v = ((const float4*)x)[(size_t)grow * 32 + c4];
        f16x4 h; h.x = (_Float16)v.x; h.y = (_Float16)v.y; h.z = (_Float16)v.z; h.w = (_Float16)v.w;
        int off = (r * 256 + c4 * 8) ^ ((r & 7) << 4);
        *(f16x4*)((char*)myX + off) = h;
    }
    __syncthreads();

    f32x4 acc[4];
    #pragma unroll
    for (int ct = 0; ct < 4; ++ct) acc[ct] = (f32x4){0.f, 0.f, 0.f, 0.f};

    int arow = lane & 15;
    #pragma unroll
    for (int ks = 0; ks < 4; ++ks) {
        int off = (arow * 256 + kg * 16 + ks * 64) ^ ((arow & 7) << 4);
        f16x8 af = *(const f16x8*)((const char*)myX + off);
        #pragma unroll
        for (int ct = 0; ct < 4; ++ct)
            acc[ct] = __builtin_amdgcn_mfma_f32_16x16x32_f16(af, bfrag[ks][ct], acc[ct], 0, 0, 0);
    }

    int crow0 = row0 + kg * 4;
    #pragma unroll
    for (int r = 0; r < 4; ++r) {
        int gr = crow0 + r;
        if (gr < n) {
            float dv = dinv[gr];
            #pragma unroll
            for (int ct = 0; ct < 4; ++ct)
                h0[(size_t)gr * HID + ct * 16 + col] = (_Float16)(acc[ct][r] * dv);
        }
    }
}

// ---------------- GEMM2 (MFMA f16): g2 = (h1 @ W2) * dinv[row], in/out f16 ----------------

__global__ __launch_bounds__(256) void k_gemm2(const _Float16* __restrict__ h1,
                                               const _Float16* __restrict__ W2T,
                                               const float* __restrict__ dinv,
                                               _Float16* __restrict__ h2, int n) {
    __shared__ _Float16 sX[4][16 * HID];   // 8 KB total
    int tid  = threadIdx.x;
    int wave = tid >> 6, lane = tid & 63;
    int row0 = blockIdx.x * 64 + wave * 16;
    int col  = lane & 15, kg = lane >> 4;

    f16x8 bfrag[2][4];
    #pragma unroll
    for (int ks = 0; ks < 2; ++ks)
        #pragma unroll
        for (int ct = 0; ct < 4; ++ct)
            bfrag[ks][ct] = *(const f16x8*)(W2T + (ct * 16 + col) * HID + ks * 32 + kg * 8);

    _Float16* myX = sX[wave];
    #pragma unroll
    for (int it = 0; it < 4; ++it) {
        int idx = it * 64 + lane;
        int r = idx >> 4, c4 = idx & 15;
        int grow = row0 + r;
        f16x4 h = (f16x4){0, 0, 0, 0};
        if (grow < n) h = ((const f16x4*)h1)[(size_t)grow * 16 + c4];
        int off = (r * 128 + c4 * 8) ^ ((r & 7) << 4);
        *(f16x4*)((char*)myX + off) = h;
    }
    __syncthreads();

    f32x4 acc[4];
    #pragma unroll
    for (int ct = 0; ct < 4; ++ct) acc[ct] = (f32x4){0.f, 0.f, 0.f, 0.f};

    int arow = lane & 15;
    #pragma unroll
    for (int ks = 0; ks < 2; ++ks) {
        int off = (arow * 128 + kg * 16 + ks * 64) ^ ((arow & 7) << 4);
        f16x8 af = *(const f16x8*)((const char*)myX + off);
        #pragma unroll
        for (int ct = 0; ct < 4; ++ct)
            acc[ct] = __builtin_amdgcn_mfma_f32_16x16x32_f16(af, bfrag[ks][ct], acc[ct], 0, 0, 0);
    }

    int crow0 = row0 + kg * 4;
    #pragma unroll
    for (int r = 0; r < 4; ++r) {
        int gr = crow0 + r;
        if (gr < n) {
            float dv = dinv[gr];
            #pragma unroll
            for (int ct = 0; ct < 4; ++ct)
                h2[(size_t)gr * HID + ct * 16 + col] = (_Float16)(acc[ct][r] * dv);
        }
    }
}

// ---------------- CSR propagate, 8 nodes per wave ----------------
// lane layout: group g = lane>>3 (node wave*8+g), gl = lane&7 (features gl*8..gl*8+7)
// one VMEM gather instruction covers 8 edges (one per group), 1 KB.

__global__ __launch_bounds__(256) void k_prop1(const int* __restrict__ rowOff,
                                               const int2* __restrict__ sedge,
                                               const _Float16* __restrict__ hin,
                                               const float* __restrict__ dinv,
                                               const float* __restrict__ b1,
                                               _Float16* __restrict__ hout, int n) {
    int wave = (blockIdx.x * blockDim.x + threadIdx.x) >> 6;
    int lane = threadIdx.x & 63;
    int g    = lane >> 3;
    int gl   = lane & 7;
    int node = wave * 8 + g;
    bool valid = node < n;
    int nd = valid ? node : 0;

    int start = rowOff[nd];
    int end   = valid ? rowOff[nd + 1] : start;
    float di  = dinv[nd];
    float4 bbA = ((const float4*)b1)[gl * 2];
    float4 bbB = ((const float4*)b1)[gl * 2 + 1];

    f16x8 sv = *(const f16x8*)(hin + (size_t)nd * HID + gl * 8);
    float a[8];
    #pragma unroll
    for (int t = 0; t < 8; ++t) a[t] = (float)sv[t];

    int j = start;
    for (; j + 4 <= end; j += 4) {
        int2 e0 = sedge[j], e1 = sedge[j + 1], e2 = sedge[j + 2], e3 = sedge[j + 3];
        f16x8 v0 = *(const f16x8*)(hin + (size_t)e0.x * HID + gl * 8);
        f16x8 v1 = *(const f16x8*)(hin + (size_t)e1.x * HID + gl * 8);
        f16x8 v2 = *(const f16x8*)(hin + (size_t)e2.x * HID + gl * 8);
        f16x8 v3 = *(const f16x8*)(hin + (size_t)e3.x * HID + gl * 8);
        float w0 = __int_as_float(e0.y), w1 = __int_as_float(e1.y);
        float w2 = __int_as_float(e2.y), w3 = __int_as_float(e3.y);
        #pragma unroll
        for (int t = 0; t < 8; ++t) a[t] = fmaf((float)v0[t], w0, a[t]);
        #pragma unroll
        for (int t = 0; t < 8; ++t) a[t] = fmaf((float)v1[t], w1, a[t]);
        #pragma unroll
        for (int t = 0; t < 8; ++t) a[t] = fmaf((float)v2[t], w2, a[t]);
        #pragma unroll
        for (int t = 0; t < 8; ++t) a[t] = fmaf((float)v3[t], w3, a[t]);
    }
    if (j < end) {
        #pragma unroll
        for (int k = 0; k < 4; ++k) {
            int idx = j + k;
            int cl  = idx < end ? idx : j;
            int2 ed = sedge[cl];
            float w = idx < end ? __int_as_float(ed.y) : 0.0f;
            f16x8 v = *(const f16x8*)(hin + (size_t)ed.x * HID + gl * 8);
            #pragma unroll
            for (int t = 0; t < 8; ++t) a[t] = fmaf((float)v[t], w, a[t]);
        }
    }

    if (valid) {
        f16x8 o;
        o[0] = (_Float16)fmaxf(fmaf(a[0], di, bbA.x), 0.0f);
        o[1] = (_Float16)fmaxf(fmaf(a[1], di, bbA.y), 0.0f);
        o[2] = (_Float16)fmaxf(fmaf(a[2], di, bbA.z), 0.0f);
        o[3] = (_Float16)fmaxf(fmaf(a[3], di, bbA.w), 0.0f);
        o[4] = (_Float16)fmaxf(fmaf(a[4], di, bbB.x), 0.0f);
        o[5] = (_Float16)fmaxf(fmaf(a[5], di, bbB.y), 0.0f);
        o[6] = (_Float16)fmaxf(fmaf(a[6], di, bbB.z), 0.0f);
        o[7] = (_Float16)fmaxf(fmaf(a[7], di, bbB.w), 0.0f);
        *(f16x8*)(hout + (size_t)node * HID + gl * 8) = o;
    }
}

__global__ __launch_bounds__(256) void k_prop2_final(const int* __restrict__ rowOff,
                                                     const int2* __restrict__ sedge,
                                                     const _Float16* __restrict__ hin,
                                                     const float* __restrict__ dinv,
                                                     const float* __restrict__ b2,
                                                     const float* __restrict__ Wl,
                                                     const float* __restrict__ bl,
                                                     float* __restrict__ out, int n) {
    int wave = (blockIdx.x * blockDim.x + threadIdx.x) >> 6;
    int lane = threadIdx.x & 63;
    int g    = lane >> 3;
    int gl   = lane & 7;
    int node = wave * 8 + g;
    bool valid = node < n;
    int nd = valid ? node : 0;

    int start = rowOff[nd];
    int end   = valid ? rowOff[nd + 1] : start;
    float di  = dinv[nd];
    float4 bbA = ((const float4*)b2)[gl * 2];
    float4 bbB = ((const float4*)b2)[gl * 2 + 1];
    float4 wlA = ((const float4*)Wl)[gl * 2];
    float4 wlB = ((const float4*)Wl)[gl * 2 + 1];

    f16x8 sv = *(const f16x8*)(hin + (size_t)nd * HID + gl * 8);
    float a[8];
    #pragma unroll
    for (int t = 0; t < 8; ++t) a[t] = (float)sv[t];

    int j = start;
    for (; j + 4 <= end; j += 4) {
        int2 e0 = sedge[j], e1 = sedge[j + 1], e2 = sedge[j + 2], e3 = sedge[j + 3];
        f16x8 v0 = *(const f16x8*)(hin + (size_t)e0.x * HID + gl * 8);
        f16x8 v1 = *(const f16x8*)(hin + (size_t)e1.x * HID + gl * 8);
        f16x8 v2 = *(const f16x8*)(hin + (size_t)e2.x * HID + gl * 8);
        f16x8 v3 = *(const f16x8*)(hin + (size_t)e3.x * HID + gl * 8);
        float w0 = __int_as_float(e0.y), w1 = __int_as_float(e1.y);
        float w2 = __int_as_float(e2.y), w3 = __int_as_float(e3.y);
        #pragma unroll
        for (int t = 0; t < 8; ++t) a[t] = fmaf((float)v0[t], w0, a[t]);
        #pragma unroll
        for (int t = 0; t < 8; ++t) a[t] = fmaf((float)v1[t], w1, a[t]);
        #pragma unroll
        for (int t = 0; t < 8; ++t) a[t] = fmaf((float)v2[t], w2, a[t]);
        #pragma unroll
        for (int t = 0; t < 8; ++t) a[t] = fmaf((float)v3[t], w3, a[t]);
    }
    if (j < end) {
        #pragma unroll
        for (int k = 0; k < 4; ++k) {
            int idx = j + k;
            int cl  = idx < end ? idx : j;
            int2 ed = sedge[cl];
            float w = idx < end ? __int_as_float(ed.y) : 0.0f;
            f16x8 v = *(const f16x8*)(hin + (size_t)ed.x * HID + gl * 8);
            #pragma unroll
            for (int t = 0; t < 8; ++t) a[t] = fmaf((float)v[t], w, a[t]);
        }
    }

    float bb[8] = {bbA.x, bbA.y, bbA.z, bbA.w, bbB.x, bbB.y, bbB.z, bbB.w};
    float wl[8] = {wlA.x, wlA.y, wlA.z, wlA.w, wlB.x, wlB.y, wlB.z, wlB.w};
    float v = 0.0f;
    #pragma unroll
    for (int t = 0; t < 8; ++t)
        v += fmaxf(fmaf(a[t], di, bb[t]), 0.0f) * wl[t];
    #pragma unroll
    for (int off = 1; off < 8; off <<= 1)
        v += __shfl_xor(v, off);
    if (valid && gl == 0) out[node] = v + bl[0];
}

// ---------------- launch ----------------

static inline char* align16(char* p) {
    return (char*)(((uintptr_t)p + 15) & ~(uintptr_t)15);
}

extern "C" void kernel_launch(void* const* d_in, const int* in_sizes, int n_in,
                              void* d_out, int out_size, void* d_ws, size_t ws_size,
                              hipStream_t stream) {
    const float* x   = (const float*)d_in[0];
    const int*   ei  = (const int*)d_in[1];
    const float* ew  = (const float*)d_in[2];
    const float* W1  = (const float*)d_in[3];
    const float* b1  = (const float*)d_in[4];
    const float* W2  = (const float*)d_in[5];
    const float* b2  = (const float*)d_in[6];
    const float* Wl  = (const float*)d_in[7];
    const float* bl  = (const float*)d_in[8];

    const int n = in_sizes[0] / IN_DIM;   // 100000
    const int e = in_sizes[2];            // 1000000
    const int* src = ei;
    const int* dst = ei + e;

    float* out = (float*)d_out;
    const int B256 = 256;
    const int nScanBlocks = (n + SCAN_B - 1) / SCAN_B;

    // workspace layout (16B-aligned slices)
    char* p = (char*)d_ws;
    int2*     sedge    = (int2*)p;            p += (size_t)e * 8;
    float*    dinv     = (float*)p;           p += (size_t)n * 4;
    int*      offsets  = (int*)p;             p += ((size_t)n + 1) * 4;
    p = align16(p);
    int*      bsums    = (int*)p;             p += 512 * 4;
    int*      rank     = (int*)p;             p += (size_t)e * 4;
    p = align16(p);
    int*      counts_s = (int*)p;             p += (size_t)NSTRIPE * n * 4;
    int*      P        = (int*)p;             p += (size_t)NSTRIPE * n * 4;
    _Float16* W1T      = (_Float16*)p;        p += IN_DIM * HID * 2;
    _Float16* W2T      = (_Float16*)p;        p += HID * HID * 2;
    p = align16(p);
    _Float16* A        = (_Float16*)p;        p += (size_t)n * HID * 2;
    _Float16* B        = (_Float16*)p;        p += (size_t)n * HID * 2;

    k_prep_w<<<(IN_DIM * HID + B256 - 1) / B256, B256, 0, stream>>>(W1, W2, W1T, W2T);

    hipMemsetAsync(counts_s, 0, (size_t)NSTRIPE * n * 4, stream);

    // striped histogram: 1 atomic per edge, 16x less line contention
    k_hist_rank<<<(e + B256 - 1) / B256, B256, 0, stream>>>(dst, counts_s, rank, n, e);

    // per-node stripe prefix + totals
    k_stripe_scan<<<(n + B256 - 1) / B256, B256, 0, stream>>>(counts_s, P, offsets, n);

    // exclusive scan of totals -> row starts; fold row starts into P
    k_scan1<<<nScanBlocks, SCAN_B, 0, stream>>>(offsets, bsums, n);
    k_scan2<<<1, 512, 0, stream>>>(bsums, nScanBlocks);
    k_scan3_fix<<<nScanBlocks, SCAN_B, 0, stream>>>(offsets, bsums, P, n, e);

    // atomic-free scatter (packed edges)
    k_scatter<<<(e + B256 - 1) / B256, B256, 0, stream>>>(src, dst, ew, rank, P, sedge, e);

    // weighted degree from sorted weights -> dinv
    k_deg_dinv<<<(n + B256 - 1) / B256, B256, 0, stream>>>(offsets, sedge, dinv, n);

    const int gemmBlocks = (n + 63) / 64;
    const int propBlocks = (n + 31) / 32;   // 32 nodes per 256-thread block

    k_gemm1<<<gemmBlocks, B256, 0, stream>>>(x, W1T, dinv, A, n);
    k_prop1<<<propBlocks, B256, 0, stream>>>(offsets, sedge, A, dinv, b1, B, n);

    k_gemm2<<<gemmBlocks, B256, 0, stream>>>(B, W2T, dinv, A, n);
    k_prop2_final<<<propBlocks, B256, 0, stream>>>(offsets, sedge, A, dinv,
                                                   b2, Wl, bl, out, n);
}

// Round 8
// 199.950 us; speedup vs baseline: 1.0390x; 1.0390x over previous
//
#include <hip/hip_runtime.h>

#define IN_DIM 128
#define HID    64
#define SCAN_B 256
#define RSIZE  16384      // nodes per LDS range (64 KB int counters)
#define CSHIFT 14         // edges per chunk = 16384
#define CSIZE  (1 << CSHIFT)
#define NCMAX  64

typedef __attribute__((ext_vector_type(4))) _Float16 f16x4;
typedef __attribute__((ext_vector_type(8))) _Float16 f16x8;
typedef __attribute__((ext_vector_type(4))) float    f32x4;

// ---------------- weight prep: f32 -> f16, transposed ----------------
__global__ void k_prep_w(const float* __restrict__ W1, const float* __restrict__ W2,
                         _Float16* __restrict__ W1T, _Float16* __restrict__ W2T) {
    int i = blockIdx.x * blockDim.x + threadIdx.x;
    if (i < IN_DIM * HID) { int k = i >> 6, c = i & 63; W1T[c * IN_DIM + k] = (_Float16)W1[i]; }
    if (i < HID * HID)    { int k = i >> 6, c = i & 63; W2T[c * HID + k]    = (_Float16)W2[i]; }
}

// ---------------- LDS-binned histogram + rank (NO global atomics) ----------------
// grid = (nChunks, nRanges); block (c,r) counts chunk c's edges whose dst is in
// range r, capturing per-edge rank via returning LDS atomics.
__global__ __launch_bounds__(256) void k_bin_hist(const int* __restrict__ dst,
                                                  unsigned short* __restrict__ hist16,
                                                  int* __restrict__ rank,
                                                  int n, int e) {
    __shared__ int cnt[RSIZE];   // 64 KB
    int c = blockIdx.x, r = blockIdx.y;
    int tid = threadIdx.x;
    int4* c4 = (int4*)cnt;
    #pragma unroll
    for (int k = 0; k < RSIZE / 4 / 256; ++k) c4[tid + k * 256] = make_int4(0, 0, 0, 0);
    __syncthreads();

    int base = r * RSIZE;
    int i0 = c << CSHIFT;
    int i1 = min(e, i0 + CSIZE);
    for (int i = i0 + tid; i < i1; i += 256) {
        int d = dst[i];
        unsigned rel = (unsigned)(d - base);
        if (rel < RSIZE) rank[i] = atomicAdd(&cnt[rel], 1);
    }
    __syncthreads();

    size_t hb = (size_t)c * n;
    for (int j = tid; j < RSIZE; j += 256) {
        int v = base + j;
        if (v < n) hist16[hb + v] = (unsigned short)cnt[j];
    }
}

// per-node prefix over chunks; hist16[c][v] -> exclusive prefix, offsets[v] = total
__global__ void k_chunk_scan(unsigned short* __restrict__ hist16,
                             int* __restrict__ offsets, int n, int nc) {
    int v = blockIdx.x * blockDim.x + threadIdx.x;
    if (v >= n) return;
    int run = 0;
    for (int c = 0; c < nc; ++c) {
        size_t idx = (size_t)c * n + v;
        int t = hist16[idx];
        hist16[idx] = (unsigned short)run;
        run += t;
    }
    offsets[v] = run;
}

// ---------------- scans ----------------
__global__ __launch_bounds__(SCAN_B) void k_scan1(int* __restrict__ data,
                                                  int* __restrict__ blockSums, int n) {
    __shared__ int s[SCAN_B];
    int tid = threadIdx.x;
    int gid = blockIdx.x * SCAN_B + tid;
    int v = (gid < n) ? data[gid] : 0;
    s[tid] = v;
    __syncthreads();
    for (int off = 1; off < SCAN_B; off <<= 1) {
        int t = (tid >= off) ? s[tid - off] : 0;
        __syncthreads();
        s[tid] += t;
        __syncthreads();
    }
    if (gid < n) data[gid] = s[tid] - v;
    if (tid == SCAN_B - 1) blockSums[blockIdx.x] = s[tid];
}

__global__ __launch_bounds__(512) void k_scan2(int* __restrict__ blockSums, int nb) {
    __shared__ int s[512];
    int tid = threadIdx.x;
    int v = (tid < nb) ? blockSums[tid] : 0;
    s[tid] = v;
    __syncthreads();
    for (int off = 1; off < 512; off <<= 1) {
        int t = (tid >= off) ? s[tid - off] : 0;
        __syncthreads();
        s[tid] += t;
        __syncthreads();
    }
    if (tid < nb) blockSums[tid] = s[tid] - v;
}

// scan fixup; also writes the terminator offsets[n] = e
__global__ __launch_bounds__(SCAN_B) void k_scan3(int* __restrict__ data,
                                                  const int* __restrict__ blockSums,
                                                  int n, int e) {
    int gid = blockIdx.x * SCAN_B + threadIdx.x;
    if (gid < n) {
        data[gid] += blockSums[blockIdx.x];
        if (gid == n - 1) data[n] = e;
    }
}

// ---------------- atomic-free scatter: pos = rowStart + chunkPrefix + rank ----------------
__global__ void k_scatter(const int* __restrict__ src, const int* __restrict__ dst,
                          const float* __restrict__ ew, const int* __restrict__ rank,
                          const int* __restrict__ offsets,
                          const unsigned short* __restrict__ hist16,
                          int2* __restrict__ sedge, int n, int e) {
    int i = blockIdx.x * blockDim.x + threadIdx.x;
    if (i >= e) return;
    int d = dst[i];
    int c = i >> CSHIFT;
    int pos = offsets[d] + (int)hist16[(size_t)c * n + d] + rank[i];
    sedge[pos] = make_int2(src[i], __float_as_int(ew[i]));
}

// ---------------- weighted degree from sorted weights + dinv ----------------
__global__ void k_deg_dinv(const int* __restrict__ rowOff, const int2* __restrict__ sedge,
                           float* __restrict__ dinv, int n) {
    int v = blockIdx.x * blockDim.x + threadIdx.x;
    if (v >= n) return;
    int s = rowOff[v], t = rowOff[v + 1];
    float a = 1.0f;                         // self-loop weight
    for (int j = s; j < t; ++j) a += __int_as_float(sedge[j].y);
    dinv[v] = rsqrtf(a);
}

// ---------------- GEMM1 (MFMA f16): g1 = (x @ W1) * dinv[row], out f16 ----------------

__global__ __launch_bounds__(256) void k_gemm1(const float* __restrict__ x,
                                               const _Float16* __restrict__ W1T,
                                               const float* __restrict__ dinv,
                                               _Float16* __restrict__ h0, int n) {
    __shared__ _Float16 sX[4][16 * IN_DIM];   // 16 KB total
    int tid  = threadIdx.x;
    int wave = tid >> 6, lane = tid & 63;
    int row0 = blockIdx.x * 64 + wave * 16;
    int col  = lane & 15, kg = lane >> 4;

    f16x8 bfrag[4][4];
    #pragma unroll
    for (int ks = 0; ks < 4; ++ks)
        #pragma unroll
        for (int ct = 0; ct < 4; ++ct)
            bfrag[ks][ct] = *(const f16x8*)(W1T + (ct * 16 + col) * IN_DIM + ks * 32 + kg * 8);

    _Float16* myX = sX[wave];
    #pragma unroll
    for (int it = 0; it < 8; ++it) {
        int idx = it * 64 + lane;
        int r = idx >> 5, c4 = idx & 31;
        int grow = row0 + r;
        float4 v = make_float4(0.f, 0.f, 0.f, 0.f);
        if (grow < n) v = ((const float4*)x)[(size_t)grow * 32 + c4];
        f16x4 h; h.x = (_Float16)v.x; h.y = (_Float16)v.y; h.z = (_Float16)v.z; h.w = (_Float16)v.w;
        int off = (r * 256 + c4 * 8) ^ ((r & 7) << 4);
        *(f16x4*)((char*)myX + off) = h;
    }
    __syncthreads();

    f32x4 acc[4];
    #pragma unroll
    for (int ct = 0; ct < 4; ++ct) acc[ct] = (f32x4){0.f, 0.f, 0.f, 0.f};

    int arow = lane & 15;
    #pragma unroll
    for (int ks = 0; ks < 4; ++ks) {
        int off = (arow * 256 + kg * 16 + ks * 64) ^ ((arow & 7) << 4);
        f16x8 af = *(const f16x8*)((const char*)myX + off);
        #pragma unroll
        for (int ct = 0; ct < 4; ++ct)
            acc[ct] = __builtin_amdgcn_mfma_f32_16x16x32_f16(af, bfrag[ks][ct], acc[ct], 0, 0, 0);
    }

    int crow0 = row0 + kg * 4;
    #pragma unroll
    for (int r = 0; r < 4; ++r) {
        int gr = crow0 + r;
        if (gr < n) {
            float dv = dinv[gr];
            #pragma unroll
            for (int ct = 0; ct < 4; ++ct)
                h0[(size_t)gr * HID + ct * 16 + col] = (_Float16)(acc[ct][r] * dv);
        }
    }
}

// ---------------- GEMM2 (MFMA f16): g2 = (h1 @ W2) * dinv[row], in/out f16 ----------------

__global__ __launch_bounds__(256) void k_gemm2(const _Float16* __restrict__ h1,
                                               const _Float16* __restrict__ W2T,
                                               const float* __restrict__ dinv,
                                               _Float16* __restrict__ h2, int n) {
    __shared__ _Float16 sX[4][16 * HID];   // 8 KB total
    int tid  = threadIdx.x;
    int wave = tid >> 6, lane = tid & 63;
    int row0 = blockIdx.x * 64 + wave * 16;
    int col  = lane & 15, kg = lane >> 4;

    f16x8 bfrag[2][4];
    #pragma unroll
    for (int ks = 0; ks < 2; ++ks)
        #pragma unroll
        for (int ct = 0; ct < 4; ++ct)
            bfrag[ks][ct] = *(const f16x8*)(W2T + (ct * 16 + col) * HID + ks * 32 + kg * 8);

    _Float16* myX = sX[wave];
    #pragma unroll
    for (int it = 0; it < 4; ++it) {
        int idx = it * 64 + lane;
        int r = idx >> 4, c4 = idx & 15;
        int grow = row0 + r;
        f16x4 h = (f16x4){0, 0, 0, 0};
        if (grow < n) h = ((const f16x4*)h1)[(size_t)grow * 16 + c4];
        int off = (r * 128 + c4 * 8) ^ ((r & 7) << 4);
        *(f16x4*)((char*)myX + off) = h;
    }
    __syncthreads();

    f32x4 acc[4];
    #pragma unroll
    for (int ct = 0; ct < 4; ++ct) acc[ct] = (f32x4){0.f, 0.f, 0.f, 0.f};

    int arow = lane & 15;
    #pragma unroll
    for (int ks = 0; ks < 2; ++ks) {
        int off = (arow * 128 + kg * 16 + ks * 64) ^ ((arow & 7) << 4);
        f16x8 af = *(const f16x8*)((const char*)myX + off);
        #pragma unroll
        for (int ct = 0; ct < 4; ++ct)
            acc[ct] = __builtin_amdgcn_mfma_f32_16x16x32_f16(af, bfrag[ks][ct], acc[ct], 0, 0, 0);
    }

    int crow0 = row0 + kg * 4;
    #pragma unroll
    for (int r = 0; r < 4; ++r) {
        int gr = crow0 + r;
        if (gr < n) {
            float dv = dinv[gr];
            #pragma unroll
            for (int ct = 0; ct < 4; ++ct)
                h2[(size_t)gr * HID + ct * 16 + col] = (_Float16)(acc[ct][r] * dv);
        }
    }
}

// ---------------- CSR propagate, 8 nodes per wave ----------------
// lane layout: group g = lane>>3 (node wave*8+g), gl = lane&7 (features gl*8..gl*8+7)
// one VMEM gather instruction covers 8 edges (one per group), 1 KB.

__global__ __launch_bounds__(256) void k_prop1(const int* __restrict__ rowOff,
                                               const int2* __restrict__ sedge,
                                               const _Float16* __restrict__ hin,
                                               const float* __restrict__ dinv,
                                               const float* __restrict__ b1,
                                               _Float16* __restrict__ hout, int n) {
    int wave = (blockIdx.x * blockDim.x + threadIdx.x) >> 6;
    int lane = threadIdx.x & 63;
    int g    = lane >> 3;
    int gl   = lane & 7;
    int node = wave * 8 + g;
    bool valid = node < n;
    int nd = valid ? node : 0;

    int start = rowOff[nd];
    int end   = valid ? rowOff[nd + 1] : start;
    float di  = dinv[nd];
    float4 bbA = ((const float4*)b1)[gl * 2];
    float4 bbB = ((const float4*)b1)[gl * 2 + 1];

    f16x8 sv = *(const f16x8*)(hin + (size_t)nd * HID + gl * 8);
    float a[8];
    #pragma unroll
    for (int t = 0; t < 8; ++t) a[t] = (float)sv[t];

    int j = start;
    for (; j + 4 <= end; j += 4) {
        int2 e0 = sedge[j], e1 = sedge[j + 1], e2 = sedge[j + 2], e3 = sedge[j + 3];
        f16x8 v0 = *(const f16x8*)(hin + (size_t)e0.x * HID + gl * 8);
        f16x8 v1 = *(const f16x8*)(hin + (size_t)e1.x * HID + gl * 8);
        f16x8 v2 = *(const f16x8*)(hin + (size_t)e2.x * HID + gl * 8);
        f16x8 v3 = *(const f16x8*)(hin + (size_t)e3.x * HID + gl * 8);
        float w0 = __int_as_float(e0.y), w1 = __int_as_float(e1.y);
        float w2 = __int_as_float(e2.y), w3 = __int_as_float(e3.y);
        #pragma unroll
        for (int t = 0; t < 8; ++t) a[t] = fmaf((float)v0[t], w0, a[t]);
        #pragma unroll
        for (int t = 0; t < 8; ++t) a[t] = fmaf((float)v1[t], w1, a[t]);
        #pragma unroll
        for (int t = 0; t < 8; ++t) a[t] = fmaf((float)v2[t], w2, a[t]);
        #pragma unroll
        for (int t = 0; t < 8; ++t) a[t] = fmaf((float)v3[t], w3, a[t]);
    }
    if (j < end) {
        #pragma unroll
        for (int k = 0; k < 4; ++k) {
            int idx = j + k;
            int cl  = idx < end ? idx : j;
            int2 ed = sedge[cl];
            float w = idx < end ? __int_as_float(ed.y) : 0.0f;
            f16x8 v = *(const f16x8*)(hin + (size_t)ed.x * HID + gl * 8);
            #pragma unroll
            for (int t = 0; t < 8; ++t) a[t] = fmaf((float)v[t], w, a[t]);
        }
    }

    if (valid) {
        f16x8 o;
        o[0] = (_Float16)fmaxf(fmaf(a[0], di, bbA.x), 0.0f);
        o[1] = (_Float16)fmaxf(fmaf(a[1], di, bbA.y), 0.0f);
        o[2] = (_Float16)fmaxf(fmaf(a[2], di, bbA.z), 0.0f);
        o[3] = (_Float16)fmaxf(fmaf(a[3], di, bbA.w), 0.0f);
        o[4] = (_Float16)fmaxf(fmaf(a[4], di, bbB.x), 0.0f);
        o[5] = (_Float16)fmaxf(fmaf(a[5], di, bbB.y), 0.0f);
        o[6] = (_Float16)fmaxf(fmaf(a[6], di, bbB.z), 0.0f);
        o[7] = (_Float16)fmaxf(fmaf(a[7], di, bbB.w), 0.0f);
        *(f16x8*)(hout + (size_t)node * HID + gl * 8) = o;
    }
}

__global__ __launch_bounds__(256) void k_prop2_final(const int* __restrict__ rowOff,
                                                     const int2* __restrict__ sedge,
                                                     const _Float16* __restrict__ hin,
                                                     const float* __restrict__ dinv,
                                                     const float* __restrict__ b2,
                                                     const float* __restrict__ Wl,
                                                     const float* __restrict__ bl,
                                                     float* __restrict__ out, int n) {
    int wave = (blockIdx.x * blockDim.x + threadIdx.x) >> 6;
    int lane = threadIdx.x & 63;
    int g    = lane >> 3;
    int gl   = lane & 7;
    int node = wave * 8 + g;
    bool valid = node < n;
    int nd = valid ? node : 0;

    int start = rowOff[nd];
    int end   = valid ? rowOff[nd + 1] : start;
    float di  = dinv[nd];
    float4 bbA = ((const float4*)b2)[gl * 2];
    float4 bbB = ((const float4*)b2)[gl * 2 + 1];
    float4 wlA = ((const float4*)Wl)[gl * 2];
    float4 wlB = ((const float4*)Wl)[gl * 2 + 1];

    f16x8 sv = *(const f16x8*)(hin + (size_t)nd * HID + gl * 8);
    float a[8];
    #pragma unroll
    for (int t = 0; t < 8; ++t) a[t] = (float)sv[t];

    int j = start;
    for (; j + 4 <= end; j += 4) {
        int2 e0 = sedge[j], e1 = sedge[j + 1], e2 = sedge[j + 2], e3 = sedge[j + 3];
        f16x8 v0 = *(const f16x8*)(hin + (size_t)e0.x * HID + gl * 8);
        f16x8 v1 = *(const f16x8*)(hin + (size_t)e1.x * HID + gl * 8);
        f16x8 v2 = *(const f16x8*)(hin + (size_t)e2.x * HID + gl * 8);
        f16x8 v3 = *(const f16x8*)(hin + (size_t)e3.x * HID + gl * 8);
        float w0 = __int_as_float(e0.y), w1 = __int_as_float(e1.y);
        float w2 = __int_as_float(e2.y), w3 = __int_as_float(e3.y);
        #pragma unroll
        for (int t = 0; t < 8; ++t) a[t] = fmaf((float)v0[t], w0, a[t]);
        #pragma unroll
        for (int t = 0; t < 8; ++t) a[t] = fmaf((float)v1[t], w1, a[t]);
        #pragma unroll
        for (int t = 0; t < 8; ++t) a[t] = fmaf((float)v2[t], w2, a[t]);
        #pragma unroll
        for (int t = 0; t < 8; ++t) a[t] = fmaf((float)v3[t], w3, a[t]);
    }
    if (j < end) {
        #pragma unroll
        for (int k = 0; k < 4; ++k) {
            int idx = j + k;
            int cl  = idx < end ? idx : j;
            int2 ed = sedge[cl];
            float w = idx < end ? __int_as_float(ed.y) : 0.0f;
            f16x8 v = *(const f16x8*)(hin + (size_t)ed.x * HID + gl * 8);
            #pragma unroll
            for (int t = 0; t < 8; ++t) a[t] = fmaf((float)v[t], w, a[t]);
        }
    }

    float bb[8] = {bbA.x, bbA.y, bbA.z, bbA.w, bbB.x, bbB.y, bbB.z, bbB.w};
    float wl[8] = {wlA.x, wlA.y, wlA.z, wlA.w, wlB.x, wlB.y, wlB.z, wlB.w};
    float v = 0.0f;
    #pragma unroll
    for (int t = 0; t < 8; ++t)
        v += fmaxf(fmaf(a[t], di, bb[t]), 0.0f) * wl[t];
    #pragma unroll
    for (int off = 1; off < 8; off <<= 1)
        v += __shfl_xor(v, off);
    if (valid && gl == 0) out[node] = v + bl[0];
}

// ---------------- launch ----------------

static inline char* align16(char* p) {
    return (char*)(((uintptr_t)p + 15) & ~(uintptr_t)15);
}

extern "C" void kernel_launch(void* const* d_in, const int* in_sizes, int n_in,
                              void* d_out, int out_size, void* d_ws, size_t ws_size,
                              hipStream_t stream) {
    const float* x   = (const float*)d_in[0];
    const int*   ei  = (const int*)d_in[1];
    const float* ew  = (const float*)d_in[2];
    const float* W1  = (const float*)d_in[3];
    const float* b1  = (const float*)d_in[4];
    const float* W2  = (const float*)d_in[5];
    const float* b2  = (const float*)d_in[6];
    const float* Wl  = (const float*)d_in[7];
    const float* bl  = (const float*)d_in[8];

    const int n = in_sizes[0] / IN_DIM;   // 100000
    const int e = in_sizes[2];            // 1000000
    const int* src = ei;
    const int* dst = ei + e;

    float* out = (float*)d_out;
    const int B256 = 256;
    const int nScanBlocks = (n + SCAN_B - 1) / SCAN_B;
    const int nc = (e + CSIZE - 1) >> CSHIFT;          // 62 chunks
    const int nr = (n + RSIZE - 1) / RSIZE;            // 7 ranges

    // workspace layout (16B-aligned slices)
    char* p = (char*)d_ws;
    int2*           sedge   = (int2*)p;            p += (size_t)e * 8;
    float*          dinv    = (float*)p;           p += (size_t)n * 4;
    int*            offsets = (int*)p;             p += ((size_t)n + 1) * 4;
    p = align16(p);
    int*            bsums   = (int*)p;             p += 512 * 4;
    int*            rank    = (int*)p;             p += (size_t)e * 4;
    p = align16(p);
    unsigned short* hist16  = (unsigned short*)p;  p += (size_t)NCMAX * n * 2;
    _Float16*       W1T     = (_Float16*)p;        p += IN_DIM * HID * 2;
    _Float16*       W2T     = (_Float16*)p;        p += HID * HID * 2;
    p = align16(p);
    _Float16*       A       = (_Float16*)p;        p += (size_t)n * HID * 2;
    _Float16*       B       = (_Float16*)p;        p += (size_t)n * HID * 2;

    k_prep_w<<<(IN_DIM * HID + B256 - 1) / B256, B256, 0, stream>>>(W1, W2, W1T, W2T);

    // LDS-binned histogram + rank capture: zero global atomics
    dim3 binGrid(nc, nr);
    k_bin_hist<<<binGrid, B256, 0, stream>>>(dst, hist16, rank, n, e);

    // per-node prefix over chunks -> hist16 becomes chunk prefix; offsets[v] = count
    k_chunk_scan<<<(n + B256 - 1) / B256, B256, 0, stream>>>(hist16, offsets, n, nc);

    // exclusive scan of counts -> row starts (+ terminator)
    k_scan1<<<nScanBlocks, SCAN_B, 0, stream>>>(offsets, bsums, n);
    k_scan2<<<1, 512, 0, stream>>>(bsums, nScanBlocks);
    k_scan3<<<nScanBlocks, SCAN_B, 0, stream>>>(offsets, bsums, n, e);

    // atomic-free scatter (packed edges)
    k_scatter<<<(e + B256 - 1) / B256, B256, 0, stream>>>(src, dst, ew, rank,
                                                         offsets, hist16, sedge, n, e);

    // weighted degree from sorted weights -> dinv
    k_deg_dinv<<<(n + B256 - 1) / B256, B256, 0, stream>>>(offsets, sedge, dinv, n);

    const int gemmBlocks = (n + 63) / 64;
    const int propBlocks = (n + 31) / 32;   // 32 nodes per 256-thread block

    k_gemm1<<<gemmBlocks, B256, 0, stream>>>(x, W1T, dinv, A, n);
    k_prop1<<<propBlocks, B256, 0, stream>>>(offsets, sedge, A, dinv, b1, B, n);

    k_gemm2<<<gemmBlocks, B256, 0, stream>>>(B, W2T, dinv, A, n);
    k_prop2_final<<<propBlocks, B256, 0, stream>>>(offsets, sedge, A, dinv,
                                                   b2, Wl, bl, out, n);
}